// Round 3
// baseline (328.480 us; speedup 1.0000x reference)
//
#include <hip/hip_runtime.h>
#include <hip/hip_bf16.h>

using bf16 = __hip_bfloat16;

typedef __bf16 bf16x8 __attribute__((ext_vector_type(8)));
typedef float  f32x4  __attribute__((ext_vector_type(4)));

#define QK_SCALE 0.125f  // 64^-0.5

// ---- fp32 -> bf16 bulk convert (RNE via __hip_bfloat16 ctor), float4-vectorized ----
struct alignas(8) bf16x4s { bf16 a, b, c, d; };
__global__ void f32_to_bf16_k(const float4* __restrict__ in, bf16x4s* __restrict__ out, int n4)
{
  const int i = blockIdx.x * blockDim.x + threadIdx.x;
  if (i < n4) {
    const float4 v = in[i];
    out[i] = { (bf16)v.x, (bf16)v.y, (bf16)v.z, (bf16)v.w };
  }
}

// =====================================================================================
// Generic NT GEMM: C[M,N] = alpha * A[M,K] @ B[N,K]^T (+bias), bf16 in, CT out, fp32 acc.
// A,B row-major, K contiguous. TM x TN tiles, BK=32, 256 threads = 4 waves.
// Batched via z: off = (z/nz1)*s0 + (z%nz1)*s1 for each of A,B,C.
// MFMA 16x16x32_bf16 layouts (HW-verified, guide §3):
//   A-frag: m = lane&15, k = (lane>>4)*8 + j     B-frag: n = lane&15, same k
//   C/D:    col = lane&15, row = (lane>>4)*4 + reg
// Register staging (uint4 load -> ds_write_b128); async global_load_lds deferred
// until after a PASS. LDS XOR swizzle on 16B k-groups: slot p of row r holds global
// k-group p ^ ((r>>1)&3) -> frag reads land at 2-way bank aliasing (free, m136).
// =====================================================================================
template<int TM, int TN, int WM, int WN, bool BIAS, typename CT>
__global__ __launch_bounds__(256, 2)
void gemm_nt(const bf16* __restrict__ A, const bf16* __restrict__ B,
             CT* __restrict__ C, const float* __restrict__ bias,
             int K, int lda, int ldb, int ldc,
             long sA0, long sA1, long sB0, long sB1, long sC0, long sC1,
             int nz1, float alpha)
{
  constexpr int BK = 32;
  const int z = blockIdx.z;
  A += (long)(z / nz1) * sA0 + (long)(z % nz1) * sA1;
  B += (long)(z / nz1) * sB0 + (long)(z % nz1) * sB1;
  C += (long)(z / nz1) * sC0 + (long)(z % nz1) * sC1;
  const int tm0 = blockIdx.y * TM;
  const int tn0 = blockIdx.x * TN;

  __shared__ __align__(16) bf16 lsA[TM * BK];
  __shared__ __align__(16) bf16 lsB[TN * BK];

  const int tid = threadIdx.x;
  const int w = tid >> 6, l = tid & 63;
  constexpr int WCOLS = TN / WN;
  const int wm = (w / WCOLS) * WM, wn = (w % WCOLS) * WN;
  constexpr int AM = WM / 16, AN = WN / 16;
  f32x4 acc[AM][AN] = {};
  const int kg = l >> 4, rl = l & 15;

  constexpr int RA = TM / 64, RB = TN / 64;
  const int srow0 = tid >> 2;          // staged row within a 64-row group
  const int scol = tid & 3;            // LDS 16B slot

  for (int k0 = 0; k0 < K; k0 += BK) {
    uint4 ra[RA], rb[RB];
#pragma unroll
    for (int r = 0; r < RA; ++r) {
      const int row = r * 64 + srow0;
      const int col8 = scol ^ ((row >> 1) & 3);  // XOR swizzle on global side
      ra[r] = *(const uint4*)(A + (long)(tm0 + row) * lda + (k0 + col8 * 8));
    }
#pragma unroll
    for (int r = 0; r < RB; ++r) {
      const int row = r * 64 + srow0;
      const int col8 = scol ^ ((row >> 1) & 3);
      rb[r] = *(const uint4*)(B + (long)(tn0 + row) * ldb + (k0 + col8 * 8));
    }
#pragma unroll
    for (int r = 0; r < RA; ++r)
      *(uint4*)&lsA[(r * 64 + srow0) * BK + scol * 8] = ra[r];
#pragma unroll
    for (int r = 0; r < RB; ++r)
      *(uint4*)&lsB[(r * 64 + srow0) * BK + scol * 8] = rb[r];
    __syncthreads();

    bf16x8 af[AM], bfr[AN];
#pragma unroll
    for (int i = 0; i < AM; ++i) {
      const int m = wm + i * 16 + rl;
      const int p = kg ^ ((m >> 1) & 3);
      af[i] = *(const bf16x8*)&lsA[m * BK + p * 8];
    }
#pragma unroll
    for (int j = 0; j < AN; ++j) {
      const int n = wn + j * 16 + rl;
      const int p = kg ^ ((n >> 1) & 3);
      bfr[j] = *(const bf16x8*)&lsB[n * BK + p * 8];
    }
#pragma unroll
    for (int i = 0; i < AM; ++i)
#pragma unroll
      for (int j = 0; j < AN; ++j)
        acc[i][j] = __builtin_amdgcn_mfma_f32_16x16x32_bf16(af[i], bfr[j], acc[i][j], 0, 0, 0);
    __syncthreads();
  }

#pragma unroll
  for (int i = 0; i < AM; ++i) {
#pragma unroll
    for (int j = 0; j < AN; ++j) {
      const int col = tn0 + wn + j * 16 + rl;
      float bv = 0.f;
      if (BIAS) bv = bias[col];
#pragma unroll
      for (int v = 0; v < 4; ++v) {
        const int row = tm0 + wm + i * 16 + (l >> 4) * 4 + v;
        C[(long)row * ldc + col] = (CT)(acc[i][j][v] * alpha + bv);
      }
    }
  }
}

// =====================================================================================
// Batched transpose + convert: out[C x R](bf16) = (bf16)in[R x C]^T. 32x32 LDS tiles.
// TI = float (weight transposes, fused fp32->bf16) or bf16 (V^T extraction).
// =====================================================================================
template<typename TI>
__global__ void transpose_k(const TI* __restrict__ in, bf16* __restrict__ out,
                            int ldi, int ldo,
                            long sI0, long sI1, long sO0, long sO1, int nz1)
{
  __shared__ bf16 t[32][33];
  const int z = blockIdx.z;
  in  += (long)(z / nz1) * sI0 + (long)(z % nz1) * sI1;
  out += (long)(z / nz1) * sO0 + (long)(z % nz1) * sO1;
  const int c0 = blockIdx.x * 32, r0 = blockIdx.y * 32;
  const int x = threadIdx.x, y = threadIdx.y;
#pragma unroll
  for (int dy = 0; dy < 32; dy += 8)
    t[y + dy][x] = (bf16)(float)in[(long)(r0 + y + dy) * ldi + c0 + x];
  __syncthreads();
#pragma unroll
  for (int dy = 0; dy < 32; dy += 8)
    out[(long)(c0 + y + dy) * ldo + r0 + x] = t[x][y + dy];
}

// =====================================================================================
// Fused talking-heads middle: per (b, i) row of S[4,16,1024,1024] (bf16, IN PLACE):
//   Smix[g,:] = sum_h mix_pre[h,g] * S[h,:]   (fp32 regs)
//   p[g,:]    = softmax_j(Smix[g,:])          (wave shuffle reductions)
//   P[G,:]    = sum_g mix_post[g,G] * p[g,:]  -> overwrite S row (same WG owns it)
// 256 threads = 4 waves; wave w owns heads g = 4w..4w+3; lane handles 16 j values.
// =====================================================================================
__global__ __launch_bounds__(256)
void mix_softmax_mix(bf16* __restrict__ S,
                     const float* __restrict__ mixpre, const float* __restrict__ mixpost)
{
  __shared__ __align__(16) bf16 lS[16 * 1024];   // 32 KB, reused as p-buffer
  __shared__ float pre[256], post[256];
  const int i = blockIdx.x, b = blockIdx.y;
  const int tid = threadIdx.x;
  pre[tid]  = mixpre[tid];
  post[tid] = mixpost[tid];
  const long hstr = 1024L * 1024L;
  bf16* Srow = S + (long)b * 16 * hstr + (long)i * 1024;

  for (int u = tid; u < 2048; u += 256) {
    const int h = u >> 7, jg = (u & 127) * 8;
    *(uint4*)&lS[h * 1024 + jg] = *(const uint4*)&Srow[(long)h * hstr + jg];
  }
  __syncthreads();

  const int w = tid >> 6, l = tid & 63;

  float sv[4][16];
#pragma unroll
  for (int gi = 0; gi < 4; ++gi)
#pragma unroll
    for (int jj = 0; jj < 16; ++jj) sv[gi][jj] = 0.f;
  for (int h = 0; h < 16; ++h) {
    float xv[16];
#pragma unroll
    for (int jj = 0; jj < 16; ++jj) xv[jj] = (float)lS[h * 1024 + jj * 64 + l];
#pragma unroll
    for (int gi = 0; gi < 4; ++gi) {
      const float c = pre[h * 16 + w * 4 + gi];
#pragma unroll
      for (int jj = 0; jj < 16; ++jj) sv[gi][jj] += c * xv[jj];
    }
  }

#pragma unroll
  for (int gi = 0; gi < 4; ++gi) {
    float mx = -1e30f;
#pragma unroll
    for (int jj = 0; jj < 16; ++jj) mx = fmaxf(mx, sv[gi][jj]);
#pragma unroll
    for (int off = 32; off; off >>= 1) mx = fmaxf(mx, __shfl_xor(mx, off, 64));
    float sum = 0.f;
#pragma unroll
    for (int jj = 0; jj < 16; ++jj) {
      const float e = __expf(sv[gi][jj] - mx);
      sv[gi][jj] = e;
      sum += e;
    }
#pragma unroll
    for (int off = 32; off; off >>= 1) sum += __shfl_xor(sum, off, 64);
    const float inv = 1.f / sum;
#pragma unroll
    for (int jj = 0; jj < 16; ++jj) sv[gi][jj] *= inv;
  }

  __syncthreads();  // everyone done READING lS before overwriting it with p
#pragma unroll
  for (int gi = 0; gi < 4; ++gi) {
    const int g = w * 4 + gi;
#pragma unroll
    for (int jj = 0; jj < 16; ++jj) lS[g * 1024 + jj * 64 + l] = (bf16)sv[gi][jj];
  }
  __syncthreads();

  float ov[4][16];
#pragma unroll
  for (int Gi = 0; Gi < 4; ++Gi)
#pragma unroll
    for (int jj = 0; jj < 16; ++jj) ov[Gi][jj] = 0.f;
  for (int g = 0; g < 16; ++g) {
    float pv[16];
#pragma unroll
    for (int jj = 0; jj < 16; ++jj) pv[jj] = (float)lS[g * 1024 + jj * 64 + l];
#pragma unroll
    for (int Gi = 0; Gi < 4; ++Gi) {
      const float c = post[g * 16 + w * 4 + Gi];
#pragma unroll
      for (int jj = 0; jj < 16; ++jj) ov[Gi][jj] += c * pv[jj];
    }
  }
#pragma unroll
  for (int Gi = 0; Gi < 4; ++Gi) {
    const int G = w * 4 + Gi;
#pragma unroll
    for (int jj = 0; jj < 16; ++jj)
      Srow[(long)G * hstr + jj * 64 + l] = (bf16)ov[Gi][jj];
  }
}

// =====================================================================================
extern "C" void kernel_launch(void* const* d_in, const int* in_sizes, int n_in,
                              void* d_out, int out_size, void* d_ws, size_t ws_size,
                              hipStream_t stream)
{
  // All inputs/outputs are FP32 per the reference (setup_inputs builds float32).
  const float* x     = (const float*)d_in[0];  // [4,1024,1024]
  const float* Wq    = (const float*)d_in[1];  // [1024,1024]
  const float* Wkv   = (const float*)d_in[2];  // [1024,2048]
  const float* mpre  = (const float*)d_in[3];  // [16,16]
  const float* mpost = (const float*)d_in[4];  // [16,16]
  const float* Wo    = (const float*)d_in[5];  // [1024,1024]
  const float* bo    = (const float*)d_in[6];  // [1024]
  float* out = (float*)d_out;                  // [4,1024,1024] fp32

  char* ws = (char*)d_ws;
  const size_t MB = 1024 * 1024;
  if (ws_size < 184 * MB) return;  // need 184 MB of scratch
  bf16* xb    = (bf16*)(ws);             // [4096,1024]           8 MB
  bf16* Qbuf  = (bf16*)(ws + 8 * MB);    // [4096,1024]           8 MB
  bf16* KVbuf = (bf16*)(ws + 16 * MB);   // [4096,2048]          16 MB
  bf16* WqT   = (bf16*)(ws + 32 * MB);   // [1024,1024]           2 MB
  bf16* WkvT  = (bf16*)(ws + 34 * MB);   // [2048,1024]           4 MB
  bf16* WoT   = (bf16*)(ws + 38 * MB);   // [1024,1024]           2 MB
  bf16* VT    = (bf16*)(ws + 40 * MB);   // [4,16,64,1024]        8 MB
  bf16* Obuf  = (bf16*)(ws + 48 * MB);   // [4096,1024]           8 MB
  bf16* Sbuf  = (bf16*)(ws + 56 * MB);   // [4,16,1024,1024]    128 MB

  const dim3 tb(32, 8, 1);

  // 0) convert x to bf16
  f32_to_bf16_k<<<4096, 256, 0, stream>>>((const float4*)x, (bf16x4s*)xb, 1048576);

  // 1) weight transposes + fp32->bf16 (so all GEMMs are NT / K-contiguous)
  transpose_k<float><<<dim3(32, 32, 1), tb, 0, stream>>>(Wq,  WqT,  1024, 1024, 0, 0, 0, 0, 1);
  transpose_k<float><<<dim3(64, 32, 1), tb, 0, stream>>>(Wkv, WkvT, 2048, 1024, 0, 0, 0, 0, 1);
  transpose_k<float><<<dim3(32, 32, 1), tb, 0, stream>>>(Wo,  WoT,  1024, 1024, 0, 0, 0, 0, 1);

  // 2) projections: Q = x@Wq, KV = x@Wkv
  gemm_nt<128, 128, 64, 64, false, bf16><<<dim3(8, 32, 1), 256, 0, stream>>>(
      xb, WqT, Qbuf, nullptr, 1024, 1024, 1024, 1024, 0, 0, 0, 0, 0, 0, 1, 1.f);
  gemm_nt<128, 128, 64, 64, false, bf16><<<dim3(16, 32, 1), 256, 0, stream>>>(
      xb, WkvT, KVbuf, nullptr, 1024, 1024, 1024, 2048, 0, 0, 0, 0, 0, 0, 1, 1.f);

  // 3) V^T per (b,G): [1024,64] -> [64,1024]
  transpose_k<bf16><<<dim3(2, 32, 64), tb, 0, stream>>>(
      KVbuf + 1024, VT, 2048, 1024,
      1024L * 2048, 64, 16L * 65536, 65536, 16);

  // 4) S = SCALE * Q_bh @ K_bh^T  (z = b*16+h)
  gemm_nt<128, 128, 64, 64, false, bf16><<<dim3(8, 8, 64), 256, 0, stream>>>(
      Qbuf, KVbuf, Sbuf, nullptr, 64, 1024, 2048, 1024,
      1048576, 64, 2097152, 64, 16L * 1048576, 1048576, 16, QK_SCALE);

  // 5) fused pre-mix + softmax + post-mix, in place on S
  mix_softmax_mix<<<dim3(1024, 4, 1), 256, 0, stream>>>(Sbuf, mpre, mpost);

  // 6) O_bG = P_bG @ V_bG  (z = b*16+G), written as [b*n+i][G*64+d]
  gemm_nt<128, 64, 64, 32, false, bf16><<<dim3(1, 8, 64), 256, 0, stream>>>(
      Sbuf, VT, Obuf, nullptr, 1024, 1024, 1024, 1024,
      16L * 1048576, 1048576, 16L * 65536, 65536, 1048576, 64, 16, 1.f);

  // 7) out = O @ Wo + bo  (fp32 output + fp32 bias)
  gemm_nt<128, 128, 64, 64, true, float><<<dim3(8, 32, 1), 256, 0, stream>>>(
      Obuf, WoT, out, bo, 1024, 1024, 1024, 1024, 0, 0, 0, 0, 0, 0, 1, 1.f);
}

// Round 4
// 319.170 us; speedup vs baseline: 1.0292x; 1.0292x over previous
//
#include <hip/hip_runtime.h>
#include <hip/hip_bf16.h>

using bf16 = __hip_bfloat16;

typedef __bf16 bf16x8 __attribute__((ext_vector_type(8)));
typedef float  f32x4  __attribute__((ext_vector_type(4)));
typedef float  f32x2  __attribute__((ext_vector_type(2)));

#define QK_SCALE 0.125f  // 64^-0.5

// ---- async global->LDS, 16B per lane (wave-uniform base + lane*16 on LDS side).
// Our staging layout is lane-contiguous: lane l's LDS ptr == wavebase + l*16. ----
__device__ __forceinline__ void load_lds16(const bf16* g, bf16* l) {
  __builtin_amdgcn_global_load_lds(
      (const __attribute__((address_space(1))) unsigned int*)g,
      (__attribute__((address_space(3))) unsigned int*)l, 16, 0, 0);
}

// ---- fp32 -> bf16 bulk convert (RNE), float4-vectorized ----
struct alignas(8) bf16x4s { bf16 a, b, c, d; };
__global__ void f32_to_bf16_k(const float4* __restrict__ in, bf16x4s* __restrict__ out, int n4)
{
  const int i = blockIdx.x * blockDim.x + threadIdx.x;
  if (i < n4) {
    const float4 v = in[i];
    out[i] = { (bf16)v.x, (bf16)v.y, (bf16)v.z, (bf16)v.w };
  }
}

// =====================================================================================
// Generic NT GEMM: C[M,N] = alpha * A[M,K] @ B[N,K]^T (+bias), bf16 in, CT out, fp32 acc.
// A,B row-major, K contiguous. TM x TN tiles, BK=32, 256 threads = 4 waves.
// Batched via z: off = (z/nz1)*s0 + (z%nz1)*s1 for each of A,B,C.
// MFMA 16x16x32_bf16 layouts (HW-verified, guide §3):
//   A-frag: m = lane&15, k = (lane>>4)*8 + j     B-frag: n = lane&15, same k
//   C/D:    col = lane&15, row = (lane>>4)*4 + reg
// Staging: async global_load_lds width=16 (m97 pattern; dtype bug of r1 is fixed, and
// the LDS layout is exactly wavebase + lane*16 as the HW requires).
// LDS XOR swizzle on 16B k-groups: slot p of row r holds global k-group p ^ ((r>>1)&3)
// -> frag ds_read_b128 land at 2-way bank aliasing (free, m136).
// =====================================================================================
template<int TM, int TN, int WM, int WN, bool BIAS, typename CT>
__global__ __launch_bounds__(256, 2)
void gemm_nt(const bf16* __restrict__ A, const bf16* __restrict__ B,
             CT* __restrict__ C, const float* __restrict__ bias,
             int K, int lda, int ldb, int ldc,
             long sA0, long sA1, long sB0, long sB1, long sC0, long sC1,
             int nz1, float alpha)
{
  constexpr int BK = 32;
  const int z = blockIdx.z;
  A += (long)(z / nz1) * sA0 + (long)(z % nz1) * sA1;
  B += (long)(z / nz1) * sB0 + (long)(z % nz1) * sB1;
  C += (long)(z / nz1) * sC0 + (long)(z % nz1) * sC1;
  const int tm0 = blockIdx.y * TM;
  const int tn0 = blockIdx.x * TN;

  __shared__ __align__(16) bf16 lsA[TM * BK];
  __shared__ __align__(16) bf16 lsB[TN * BK];

  const int tid = threadIdx.x;
  const int w = tid >> 6, l = tid & 63;
  constexpr int WCOLS = TN / WN;
  const int wm = (w / WCOLS) * WM, wn = (w % WCOLS) * WN;
  constexpr int AM = WM / 16, AN = WN / 16;
  f32x4 acc[AM][AN] = {};
  const int kg = l >> 4, rl = l & 15;

  constexpr int RA = TM / 64, RB = TN / 64;
  const int srow0 = tid >> 2;          // staged row within a 64-row group
  const int scol = tid & 3;            // LDS 16B slot

  for (int k0 = 0; k0 < K; k0 += BK) {
#pragma unroll
    for (int r = 0; r < RA; ++r) {
      const int row = r * 64 + srow0;
      const int col8 = scol ^ ((row >> 1) & 3);  // XOR swizzle on global side
      load_lds16(A + (long)(tm0 + row) * lda + (k0 + col8 * 8),
                 &lsA[row * BK + scol * 8]);
    }
#pragma unroll
    for (int r = 0; r < RB; ++r) {
      const int row = r * 64 + srow0;
      const int col8 = scol ^ ((row >> 1) & 3);
      load_lds16(B + (long)(tn0 + row) * ldb + (k0 + col8 * 8),
                 &lsB[row * BK + scol * 8]);
    }
    __syncthreads();  // compiler emits vmcnt(0) drain before barrier

    bf16x8 af[AM], bfr[AN];
#pragma unroll
    for (int i = 0; i < AM; ++i) {
      const int m = wm + i * 16 + rl;
      const int p = kg ^ ((m >> 1) & 3);
      af[i] = *(const bf16x8*)&lsA[m * BK + p * 8];
    }
#pragma unroll
    for (int j = 0; j < AN; ++j) {
      const int n = wn + j * 16 + rl;
      const int p = kg ^ ((n >> 1) & 3);
      bfr[j] = *(const bf16x8*)&lsB[n * BK + p * 8];
    }
#pragma unroll
    for (int i = 0; i < AM; ++i)
#pragma unroll
      for (int j = 0; j < AN; ++j)
        acc[i][j] = __builtin_amdgcn_mfma_f32_16x16x32_bf16(af[i], bfr[j], acc[i][j], 0, 0, 0);
    __syncthreads();
  }

#pragma unroll
  for (int i = 0; i < AM; ++i) {
#pragma unroll
    for (int j = 0; j < AN; ++j) {
      const int col = tn0 + wn + j * 16 + rl;
      float bv = 0.f;
      if (BIAS) bv = bias[col];
#pragma unroll
      for (int v = 0; v < 4; ++v) {
        const int row = tm0 + wm + i * 16 + (l >> 4) * 4 + v;
        C[(long)row * ldc + col] = (CT)(acc[i][j][v] * alpha + bv);
      }
    }
  }
}

// =====================================================================================
// Batched transpose + convert: out[C x R](bf16) = (bf16)in[R x C]^T. 32x32 LDS tiles.
// =====================================================================================
template<typename TI>
__global__ void transpose_k(const TI* __restrict__ in, bf16* __restrict__ out,
                            int ldi, int ldo,
                            long sI0, long sI1, long sO0, long sO1, int nz1)
{
  __shared__ bf16 t[32][33];
  const int z = blockIdx.z;
  in  += (long)(z / nz1) * sI0 + (long)(z % nz1) * sI1;
  out += (long)(z / nz1) * sO0 + (long)(z % nz1) * sO1;
  const int c0 = blockIdx.x * 32, r0 = blockIdx.y * 32;
  const int x = threadIdx.x, y = threadIdx.y;
#pragma unroll
  for (int dy = 0; dy < 32; dy += 8)
    t[y + dy][x] = (bf16)(float)in[(long)(r0 + y + dy) * ldi + c0 + x];
  __syncthreads();
#pragma unroll
  for (int dy = 0; dy < 32; dy += 8)
    out[(long)(c0 + y + dy) * ldo + r0 + x] = t[x][y + dy];
}

// =====================================================================================
// Fused talking-heads middle, VECTORIZED: per (b,i) row of S[4,16,1024,1024] (IN PLACE).
// 4 waves; wave w: j-half = w&1 (512 j), g-octet = (w>>1)*8. Lane owns 8 contiguous j.
// All LDS/global accesses are b128 with 16B lane stride (2-way aliasing = free, m136).
// Premix reads S straight from global (coalesced; 2-wave overlap L2-absorbed).
// Mix FMAs in packed f32x2 (v_pk_fma_f32). Softmax: lane-local + 64-lane shuffle +
// 2-wave LDS combine. LDS holds only the p-buffer (32 KB).
// =====================================================================================
__global__ __launch_bounds__(256)
void mix_softmax_mix(bf16* __restrict__ S,
                     const float* __restrict__ mixpre, const float* __restrict__ mixpost)
{
  __shared__ __align__(16) bf16 lP[16 * 1024];   // post-softmax probs, 32 KB
  __shared__ float pre[256], post[256];
  __shared__ float redA[4][8], redB[4][8];
  const int i = blockIdx.x, b = blockIdx.y;
  const int tid = threadIdx.x;
  pre[tid]  = mixpre[tid];
  post[tid] = mixpost[tid];
  const long hstr = 1048576L;
  bf16* Srow = S + (long)b * 16 * hstr + (long)i * 1024;
  const int w = tid >> 6, l = tid & 63;
  const int goct = (w >> 1) * 8;
  const int j0 = (w & 1) * 512 + l * 8;
  __syncthreads();  // pre/post visible

  // ---- premix: sv[gi][:] = sum_h pre[h, goct+gi] * S[h, j0..j0+7] ----
  f32x2 sv[8][4];
#pragma unroll
  for (int gi = 0; gi < 8; ++gi)
#pragma unroll
    for (int q = 0; q < 4; ++q) sv[gi][q] = f32x2{0.f, 0.f};

  for (int h = 0; h < 16; ++h) {
    const bf16x8 raw = *(const bf16x8*)&Srow[(long)h * hstr + j0];
    f32x2 xv[4];
#pragma unroll
    for (int q = 0; q < 4; ++q) xv[q] = f32x2{(float)raw[2 * q], (float)raw[2 * q + 1]};
#pragma unroll
    for (int gi = 0; gi < 8; ++gi) {
      const float c = pre[h * 16 + goct + gi];
      const f32x2 cc = {c, c};
#pragma unroll
      for (int q = 0; q < 4; ++q) sv[gi][q] += cc * xv[q];
    }
  }

  // ---- softmax over full row per g: lane-local -> 64-lane shuffle -> 2-wave LDS ----
  float mx[8];
#pragma unroll
  for (int gi = 0; gi < 8; ++gi) {
    float m = -1e30f;
#pragma unroll
    for (int q = 0; q < 4; ++q) m = fmaxf(m, fmaxf(sv[gi][q][0], sv[gi][q][1]));
#pragma unroll
    for (int off = 32; off; off >>= 1) m = fmaxf(m, __shfl_xor(m, off, 64));
    mx[gi] = m;
  }
  if (l == 0) {
#pragma unroll
    for (int gi = 0; gi < 8; ++gi) redA[w][gi] = mx[gi];
  }
  __syncthreads();
#pragma unroll
  for (int gi = 0; gi < 8; ++gi) mx[gi] = fmaxf(redA[w][gi], redA[w ^ 1][gi]);

  float sum[8];
#pragma unroll
  for (int gi = 0; gi < 8; ++gi) {
    float s = 0.f;
#pragma unroll
    for (int q = 0; q < 4; ++q) {
#pragma unroll
      for (int e = 0; e < 2; ++e) {
        const float ev = __expf(sv[gi][q][e] - mx[gi]);
        sv[gi][q][e] = ev;
        s += ev;
      }
    }
#pragma unroll
    for (int off = 32; off; off >>= 1) s += __shfl_xor(s, off, 64);
    sum[gi] = s;
  }
  if (l == 0) {
#pragma unroll
    for (int gi = 0; gi < 8; ++gi) redB[w][gi] = sum[gi];
  }
  __syncthreads();

  // ---- normalize, write p (bf16) to LDS ----
#pragma unroll
  for (int gi = 0; gi < 8; ++gi) {
    const float inv = 1.f / (redB[w][gi] + redB[w ^ 1][gi]);
    bf16x8 pk;
#pragma unroll
    for (int q = 0; q < 4; ++q) {
      pk[2 * q]     = (__bf16)(sv[gi][q][0] * inv);
      pk[2 * q + 1] = (__bf16)(sv[gi][q][1] * inv);
    }
    *(bf16x8*)&lP[(goct + gi) * 1024 + j0] = pk;
  }
  __syncthreads();

  // ---- postmix: ov[Gi][:] = sum_g post[g, goct+Gi] * p[g, j0..j0+7]; write to S ----
  f32x2 ov[8][4];
#pragma unroll
  for (int Gi = 0; Gi < 8; ++Gi)
#pragma unroll
    for (int q = 0; q < 4; ++q) ov[Gi][q] = f32x2{0.f, 0.f};

  for (int g = 0; g < 16; ++g) {
    const bf16x8 praw = *(const bf16x8*)&lP[g * 1024 + j0];
    f32x2 pv[4];
#pragma unroll
    for (int q = 0; q < 4; ++q) pv[q] = f32x2{(float)praw[2 * q], (float)praw[2 * q + 1]};
#pragma unroll
    for (int Gi = 0; Gi < 8; ++Gi) {
      const float c = post[g * 16 + goct + Gi];
      const f32x2 cc = {c, c};
#pragma unroll
      for (int q = 0; q < 4; ++q) ov[Gi][q] += cc * pv[q];
    }
  }
#pragma unroll
  for (int Gi = 0; Gi < 8; ++Gi) {
    bf16x8 pk;
#pragma unroll
    for (int q = 0; q < 4; ++q) {
      pk[2 * q]     = (__bf16)ov[Gi][q][0];
      pk[2 * q + 1] = (__bf16)ov[Gi][q][1];
    }
    *(bf16x8*)&Srow[(long)(goct + Gi) * hstr + j0] = pk;
  }
}

// =====================================================================================
extern "C" void kernel_launch(void* const* d_in, const int* in_sizes, int n_in,
                              void* d_out, int out_size, void* d_ws, size_t ws_size,
                              hipStream_t stream)
{
  // All inputs/outputs are FP32 per the reference.
  const float* x     = (const float*)d_in[0];  // [4,1024,1024]
  const float* Wq    = (const float*)d_in[1];  // [1024,1024]
  const float* Wkv   = (const float*)d_in[2];  // [1024,2048]
  const float* mpre  = (const float*)d_in[3];  // [16,16]
  const float* mpost = (const float*)d_in[4];  // [16,16]
  const float* Wo    = (const float*)d_in[5];  // [1024,1024]
  const float* bo    = (const float*)d_in[6];  // [1024]
  float* out = (float*)d_out;                  // [4,1024,1024] fp32

  char* ws = (char*)d_ws;
  const size_t MB = 1024 * 1024;
  if (ws_size < 184 * MB) return;
  bf16* xb    = (bf16*)(ws);             // [4096,1024]           8 MB
  bf16* Qbuf  = (bf16*)(ws + 8 * MB);    // [4096,1024]           8 MB
  bf16* KVbuf = (bf16*)(ws + 16 * MB);   // [4096,2048]          16 MB
  bf16* WqT   = (bf16*)(ws + 32 * MB);   // [1024,1024]           2 MB
  bf16* WkvT  = (bf16*)(ws + 34 * MB);   // [2048,1024]           4 MB
  bf16* WoT   = (bf16*)(ws + 38 * MB);   // [1024,1024]           2 MB
  bf16* VT    = (bf16*)(ws + 40 * MB);   // [4,16,64,1024]        8 MB
  bf16* Obuf  = (bf16*)(ws + 48 * MB);   // [4096,1024]           8 MB
  bf16* Sbuf  = (bf16*)(ws + 56 * MB);   // [4,16,1024,1024]    128 MB

  const dim3 tb(32, 8, 1);

  // 0) convert x to bf16
  f32_to_bf16_k<<<4096, 256, 0, stream>>>((const float4*)x, (bf16x4s*)xb, 1048576);

  // 1) weight transposes + fp32->bf16 (so all GEMMs are NT / K-contiguous)
  transpose_k<float><<<dim3(32, 32, 1), tb, 0, stream>>>(Wq,  WqT,  1024, 1024, 0, 0, 0, 0, 1);
  transpose_k<float><<<dim3(64, 32, 1), tb, 0, stream>>>(Wkv, WkvT, 2048, 1024, 0, 0, 0, 0, 1);
  transpose_k<float><<<dim3(32, 32, 1), tb, 0, stream>>>(Wo,  WoT,  1024, 1024, 0, 0, 0, 0, 1);

  // 2) projections: Q = x@Wq, KV = x@Wkv
  gemm_nt<128, 128, 64, 64, false, bf16><<<dim3(8, 32, 1), 256, 0, stream>>>(
      xb, WqT, Qbuf, nullptr, 1024, 1024, 1024, 1024, 0, 0, 0, 0, 0, 0, 1, 1.f);
  gemm_nt<128, 128, 64, 64, false, bf16><<<dim3(16, 32, 1), 256, 0, stream>>>(
      xb, WkvT, KVbuf, nullptr, 1024, 1024, 1024, 2048, 0, 0, 0, 0, 0, 0, 1, 1.f);

  // 3) V^T per (b,G): [1024,64] -> [64,1024]
  transpose_k<bf16><<<dim3(2, 32, 64), tb, 0, stream>>>(
      KVbuf + 1024, VT, 2048, 1024,
      1024L * 2048, 64, 16L * 65536, 65536, 16);

  // 4) S = SCALE * Q_bh @ K_bh^T  (z = b*16+h)
  gemm_nt<128, 128, 64, 64, false, bf16><<<dim3(8, 8, 64), 256, 0, stream>>>(
      Qbuf, KVbuf, Sbuf, nullptr, 64, 1024, 2048, 1024,
      1048576, 64, 2097152, 64, 16L * 1048576, 1048576, 16, QK_SCALE);

  // 5) fused pre-mix + softmax + post-mix, in place on S
  mix_softmax_mix<<<dim3(1024, 4, 1), 256, 0, stream>>>(Sbuf, mpre, mpost);

  // 6) O_bG = P_bG @ V_bG  (z = b*16+G), written as [b*n+i][G*64+d]
  gemm_nt<128, 64, 64, 32, false, bf16><<<dim3(1, 8, 64), 256, 0, stream>>>(
      Sbuf, VT, Obuf, nullptr, 1024, 1024, 1024, 1024,
      16L * 1048576, 1048576, 16L * 65536, 65536, 1048576, 64, 16, 1.f);

  // 7) out = O @ Wo + bo  (fp32 output + fp32 bias)
  gemm_nt<128, 128, 64, 64, true, float><<<dim3(8, 32, 1), 256, 0, stream>>>(
      Obuf, WoT, out, bo, 1024, 1024, 1024, 1024, 0, 0, 0, 0, 0, 0, 1, 1.f);
}

// Round 5
// 298.806 us; speedup vs baseline: 1.0993x; 1.0682x over previous
//
#include <hip/hip_runtime.h>
#include <hip/hip_bf16.h>

using bf16 = __hip_bfloat16;

typedef __bf16 bf16x8 __attribute__((ext_vector_type(8)));
typedef float  f32x4  __attribute__((ext_vector_type(4)));
typedef float  f32x2  __attribute__((ext_vector_type(2)));

#define QK_SCALE 0.125f  // 64^-0.5

// ---- async global->LDS, 16B per lane (wave-uniform base + lane*16 on LDS side) ----
__device__ __forceinline__ void load_lds16(const bf16* g, bf16* l) {
  __builtin_amdgcn_global_load_lds(
      (const __attribute__((address_space(1))) unsigned int*)g,
      (__attribute__((address_space(3))) unsigned int*)l, 16, 0, 0);
}

// ---- fp32 -> bf16 bulk convert (RNE), float4-vectorized ----
struct alignas(8) bf16x4s { bf16 a, b, c, d; };
__global__ void f32_to_bf16_k(const float4* __restrict__ in, bf16x4s* __restrict__ out, int n4)
{
  const int i = blockIdx.x * blockDim.x + threadIdx.x;
  if (i < n4) {
    const float4 v = in[i];
    out[i] = { (bf16)v.x, (bf16)v.y, (bf16)v.z, (bf16)v.w };
  }
}

// =====================================================================================
// Generic NT GEMM: C[M,N] = alpha * A[M,K] @ B[N,K]^T (+bias), bf16 in, CT out, fp32 acc.
// A,B row-major, K contiguous. TM x TN tiles, BK=32, 256 threads = 4 waves.
// Batched via z: off = (z/nz1)*s0 + (z%nz1)*s1 for each of A,B,C.
// MFMA 16x16x32_bf16 layouts (HW-verified, guide §3):
//   A-frag: m = lane&15, k = (lane>>4)*8 + j     B-frag: n = lane&15, same k
//   C/D:    col = lane&15, row = (lane>>4)*4 + reg
// Staging: async global_load_lds width=16 (m97 pattern). XOR swizzle on 16B k-groups.
// Epilogue (bf16 out): LDS round-trip (pad +8) -> coalesced bf16x8 16B/lane stores.
// =====================================================================================
template<int TM, int TN, int WM, int WN, bool BIAS, typename CT>
__global__ __launch_bounds__(256, 2)
void gemm_nt(const bf16* __restrict__ A, const bf16* __restrict__ B,
             CT* __restrict__ C, const float* __restrict__ bias,
             int K, int lda, int ldb, int ldc,
             long sA0, long sA1, long sB0, long sB1, long sC0, long sC1,
             int nz1, float alpha)
{
  constexpr int BK = 32;
  constexpr int LDE = TN + 8;
  constexpr unsigned SB_STAGE = (TM + TN) * BK * 2;
  constexpr unsigned SB_EP = (sizeof(CT) == 2) ? TM * LDE * 2 : 0;
  constexpr unsigned SBYTES = SB_STAGE > SB_EP ? SB_STAGE : SB_EP;
  __shared__ __align__(16) char smem[SBYTES];
  bf16* lsA = (bf16*)smem;
  bf16* lsB = lsA + TM * BK;

  const int z = blockIdx.z;
  A += (long)(z / nz1) * sA0 + (long)(z % nz1) * sA1;
  B += (long)(z / nz1) * sB0 + (long)(z % nz1) * sB1;
  C += (long)(z / nz1) * sC0 + (long)(z % nz1) * sC1;
  const int tm0 = blockIdx.y * TM;
  const int tn0 = blockIdx.x * TN;

  const int tid = threadIdx.x;
  const int w = tid >> 6, l = tid & 63;
  constexpr int WCOLS = TN / WN;
  const int wm = (w / WCOLS) * WM, wn = (w % WCOLS) * WN;
  constexpr int AM = WM / 16, AN = WN / 16;
  f32x4 acc[AM][AN] = {};
  const int kg = l >> 4, rl = l & 15;

  constexpr int RA = TM / 64, RB = TN / 64;
  const int srow0 = tid >> 2;          // staged row within a 64-row group
  const int scol = tid & 3;            // LDS 16B slot

  for (int k0 = 0; k0 < K; k0 += BK) {
#pragma unroll
    for (int r = 0; r < RA; ++r) {
      const int row = r * 64 + srow0;
      const int col8 = scol ^ ((row >> 1) & 3);  // XOR swizzle on global side
      load_lds16(A + (long)(tm0 + row) * lda + (k0 + col8 * 8),
                 &lsA[row * BK + scol * 8]);
    }
#pragma unroll
    for (int r = 0; r < RB; ++r) {
      const int row = r * 64 + srow0;
      const int col8 = scol ^ ((row >> 1) & 3);
      load_lds16(B + (long)(tn0 + row) * ldb + (k0 + col8 * 8),
                 &lsB[row * BK + scol * 8]);
    }
    __syncthreads();

    bf16x8 af[AM], bfr[AN];
#pragma unroll
    for (int i = 0; i < AM; ++i) {
      const int m = wm + i * 16 + rl;
      const int p = kg ^ ((m >> 1) & 3);
      af[i] = *(const bf16x8*)&lsA[m * BK + p * 8];
    }
#pragma unroll
    for (int j = 0; j < AN; ++j) {
      const int n = wn + j * 16 + rl;
      const int p = kg ^ ((n >> 1) & 3);
      bfr[j] = *(const bf16x8*)&lsB[n * BK + p * 8];
    }
#pragma unroll
    for (int i = 0; i < AM; ++i)
#pragma unroll
      for (int j = 0; j < AN; ++j)
        acc[i][j] = __builtin_amdgcn_mfma_f32_16x16x32_bf16(af[i], bfr[j], acc[i][j], 0, 0, 0);
    __syncthreads();
  }

  if constexpr (sizeof(CT) == 2) {
    // ---- vectorized epilogue: acc -> LDS (padded) -> coalesced 16B stores ----
    bf16* ep = (bf16*)smem;
#pragma unroll
    for (int i = 0; i < AM; ++i) {
#pragma unroll
      for (int j = 0; j < AN; ++j) {
        const int col = wn + j * 16 + rl;
        float bv = 0.f;
        if (BIAS) bv = bias[tn0 + col];
#pragma unroll
        for (int v = 0; v < 4; ++v) {
          const int row = wm + i * 16 + (l >> 4) * 4 + v;
          ep[row * LDE + col] = (bf16)(acc[i][j][v] * alpha + bv);
        }
      }
    }
    __syncthreads();
    constexpr int CH = (TM * TN) / 2048;
#pragma unroll
    for (int c = 0; c < CH; ++c) {
      const int gidx = (c * 256 + tid) * 8;
      const int row = gidx / TN, col = gidx % TN;
      *(uint4*)&C[(long)(tm0 + row) * ldc + tn0 + col] = *(const uint4*)&ep[row * LDE + col];
    }
  } else {
    // ---- direct scalar epilogue (fp32 out) ----
#pragma unroll
    for (int i = 0; i < AM; ++i) {
#pragma unroll
      for (int j = 0; j < AN; ++j) {
        const int col = tn0 + wn + j * 16 + rl;
        float bv = 0.f;
        if (BIAS) bv = bias[col];
#pragma unroll
        for (int v = 0; v < 4; ++v) {
          const int row = tm0 + wm + i * 16 + (l >> 4) * 4 + v;
          C[(long)row * ldc + col] = (CT)(acc[i][j][v] * alpha + bv);
        }
      }
    }
  }
}

// =====================================================================================
// Batched transpose + convert: out[C x R](bf16) = (bf16)in[R x C]^T. 32x32 LDS tiles.
// =====================================================================================
template<typename TI>
__global__ void transpose_k(const TI* __restrict__ in, bf16* __restrict__ out,
                            int ldi, int ldo,
                            long sI0, long sI1, long sO0, long sO1, int nz1)
{
  __shared__ bf16 t[32][33];
  const int z = blockIdx.z;
  in  += (long)(z / nz1) * sI0 + (long)(z % nz1) * sI1;
  out += (long)(z / nz1) * sO0 + (long)(z % nz1) * sO1;
  const int c0 = blockIdx.x * 32, r0 = blockIdx.y * 32;
  const int x = threadIdx.x, y = threadIdx.y;
#pragma unroll
  for (int dy = 0; dy < 32; dy += 8)
    t[y + dy][x] = (bf16)(float)in[(long)(r0 + y + dy) * ldi + c0 + x];
  __syncthreads();
#pragma unroll
  for (int dy = 0; dy < 32; dy += 8)
    out[(long)(c0 + y + dy) * ldo + r0 + x] = t[x][y + dy];
}

// =====================================================================================
// Fused talking-heads middle, vectorized, single-barrier softmax combine.
// Per (b,i) row of S[4,16,1024,1024] (IN PLACE). 4 waves; wave w: j-half = w&1,
// g-octet = (w>>1)*8. Lane owns 8 contiguous j -> all accesses b128.
// Softmax: per-wave (m_w, s_w) -> one barrier -> rescale e^{m_w-m}/Z fold into scale.
// =====================================================================================
__global__ __launch_bounds__(256)
void mix_softmax_mix(bf16* __restrict__ S,
                     const float* __restrict__ mixpre, const float* __restrict__ mixpost)
{
  __shared__ __align__(16) bf16 lP[16 * 1024];   // post-softmax probs, 32 KB
  __shared__ float pre[256], post[256];
  __shared__ float redA[4][8], redB[4][8];
  const int i = blockIdx.x, b = blockIdx.y;
  const int tid = threadIdx.x;
  pre[tid]  = mixpre[tid];
  post[tid] = mixpost[tid];
  const long hstr = 1048576L;
  bf16* Srow = S + (long)b * 16 * hstr + (long)i * 1024;
  const int w = tid >> 6, l = tid & 63;
  const int goct = (w >> 1) * 8;
  const int j0 = (w & 1) * 512 + l * 8;
  __syncthreads();  // pre/post visible

  // ---- premix ----
  f32x2 sv[8][4];
#pragma unroll
  for (int gi = 0; gi < 8; ++gi)
#pragma unroll
    for (int q = 0; q < 4; ++q) sv[gi][q] = f32x2{0.f, 0.f};

  for (int h = 0; h < 16; ++h) {
    const bf16x8 raw = *(const bf16x8*)&Srow[(long)h * hstr + j0];
    f32x2 xv[4];
#pragma unroll
    for (int q = 0; q < 4; ++q) xv[q] = f32x2{(float)raw[2 * q], (float)raw[2 * q + 1]};
#pragma unroll
    for (int gi = 0; gi < 8; ++gi) {
      const float c = pre[h * 16 + goct + gi];
      const f32x2 cc = {c, c};
#pragma unroll
      for (int q = 0; q < 4; ++q) sv[gi][q] += cc * xv[q];
    }
  }

  // ---- per-wave softmax partials ----
  float mx[8], sw[8];
#pragma unroll
  for (int gi = 0; gi < 8; ++gi) {
    float m = -1e30f;
#pragma unroll
    for (int q = 0; q < 4; ++q) m = fmaxf(m, fmaxf(sv[gi][q][0], sv[gi][q][1]));
#pragma unroll
    for (int off = 32; off; off >>= 1) m = fmaxf(m, __shfl_xor(m, off, 64));
    mx[gi] = m;
    float s = 0.f;
#pragma unroll
    for (int q = 0; q < 4; ++q) {
#pragma unroll
      for (int e = 0; e < 2; ++e) {
        const float ev = __expf(sv[gi][q][e] - m);
        sv[gi][q][e] = ev;
        s += ev;
      }
    }
#pragma unroll
    for (int off = 32; off; off >>= 1) s += __shfl_xor(s, off, 64);
    sw[gi] = s;
  }
  if (l == 0) {
#pragma unroll
    for (int gi = 0; gi < 8; ++gi) { redA[w][gi] = mx[gi]; redB[w][gi] = sw[gi]; }
  }
  __syncthreads();

  // ---- combine (rescale trick), normalize, write p (bf16) to LDS ----
#pragma unroll
  for (int gi = 0; gi < 8; ++gi) {
    const float mo = redA[w ^ 1][gi], so = redB[w ^ 1][gi];
    const float m = fmaxf(mx[gi], mo);
    const float Z = sw[gi] * __expf(mx[gi] - m) + so * __expf(mo - m);
    const float scl = __expf(mx[gi] - m) / Z;
    bf16x8 pk;
#pragma unroll
    for (int q = 0; q < 4; ++q) {
      pk[2 * q]     = (__bf16)(sv[gi][q][0] * scl);
      pk[2 * q + 1] = (__bf16)(sv[gi][q][1] * scl);
    }
    *(bf16x8*)&lP[(goct + gi) * 1024 + j0] = pk;
  }
  __syncthreads();

  // ---- postmix; write back over S ----
  f32x2 ov[8][4];
#pragma unroll
  for (int Gi = 0; Gi < 8; ++Gi)
#pragma unroll
    for (int q = 0; q < 4; ++q) ov[Gi][q] = f32x2{0.f, 0.f};

  for (int g = 0; g < 16; ++g) {
    const bf16x8 praw = *(const bf16x8*)&lP[g * 1024 + j0];
    f32x2 pv[4];
#pragma unroll
    for (int q = 0; q < 4; ++q) pv[q] = f32x2{(float)praw[2 * q], (float)praw[2 * q + 1]};
#pragma unroll
    for (int Gi = 0; Gi < 8; ++Gi) {
      const float c = post[g * 16 + goct + Gi];
      const f32x2 cc = {c, c};
#pragma unroll
      for (int q = 0; q < 4; ++q) ov[Gi][q] += cc * pv[q];
    }
  }
#pragma unroll
  for (int Gi = 0; Gi < 8; ++Gi) {
    bf16x8 pk;
#pragma unroll
    for (int q = 0; q < 4; ++q) {
      pk[2 * q]     = (__bf16)ov[Gi][q][0];
      pk[2 * q + 1] = (__bf16)ov[Gi][q][1];
    }
    *(bf16x8*)&Srow[(long)(goct + Gi) * hstr + j0] = pk;
  }
}

// =====================================================================================
extern "C" void kernel_launch(void* const* d_in, const int* in_sizes, int n_in,
                              void* d_out, int out_size, void* d_ws, size_t ws_size,
                              hipStream_t stream)
{
  // All inputs/outputs are FP32 per the reference.
  const float* x     = (const float*)d_in[0];  // [4,1024,1024]
  const float* Wq    = (const float*)d_in[1];  // [1024,1024]
  const float* Wkv   = (const float*)d_in[2];  // [1024,2048]
  const float* mpre  = (const float*)d_in[3];  // [16,16]
  const float* mpost = (const float*)d_in[4];  // [16,16]
  const float* Wo    = (const float*)d_in[5];  // [1024,1024]
  const float* bo    = (const float*)d_in[6];  // [1024]
  float* out = (float*)d_out;                  // [4,1024,1024] fp32

  char* ws = (char*)d_ws;
  const size_t MB = 1024 * 1024;
  if (ws_size < 184 * MB) return;
  bf16* xb   = (bf16*)(ws);             // [4096,1024]           8 MB
  bf16* QKV  = (bf16*)(ws + 8 * MB);    // [4096,3072] Q|K|V    24 MB
  bf16* WT   = (bf16*)(ws + 32 * MB);   // [3072,1024] WqT|WkvT  6 MB
  bf16* WoT  = (bf16*)(ws + 38 * MB);   // [1024,1024]           2 MB
  bf16* VT   = (bf16*)(ws + 40 * MB);   // [4,16,64,1024]        8 MB
  bf16* Obuf = (bf16*)(ws + 48 * MB);   // [4096,1024]           8 MB
  bf16* Sbuf = (bf16*)(ws + 56 * MB);   // [4,16,1024,1024]    128 MB

  const dim3 tb(32, 8, 1);

  // 0) convert x to bf16
  f32_to_bf16_k<<<4096, 256, 0, stream>>>((const float4*)x, (bf16x4s*)xb, 1048576);

  // 1) weight transposes + fp32->bf16: WT = [Wq^T ; Wkv^T], WoT = Wo^T
  transpose_k<float><<<dim3(32, 32, 1), tb, 0, stream>>>(Wq,  WT,            1024, 1024, 0, 0, 0, 0, 1);
  transpose_k<float><<<dim3(64, 32, 1), tb, 0, stream>>>(Wkv, WT + 1048576,  2048, 1024, 0, 0, 0, 0, 1);
  transpose_k<float><<<dim3(32, 32, 1), tb, 0, stream>>>(Wo,  WoT,           1024, 1024, 0, 0, 0, 0, 1);

  // 2) fused projection: QKV = x @ [Wq | Wkv]   (768 blocks = 3/CU)
  gemm_nt<128, 128, 64, 64, false, bf16><<<dim3(24, 32, 1), 256, 0, stream>>>(
      xb, WT, QKV, nullptr, 1024, 1024, 1024, 3072, 0, 0, 0, 0, 0, 0, 1, 1.f);

  // 3) V^T per (b,G): [1024,64] -> [64,1024]  (V = QKV cols 2048..3071)
  transpose_k<bf16><<<dim3(2, 32, 64), tb, 0, stream>>>(
      QKV + 2048, VT, 3072, 1024,
      3145728, 64, 16L * 65536, 65536, 16);

  // 4) S = SCALE * Q_bh @ K_bh^T  (z = b*16+h; Q = QKV cols 0.., K = cols 1024..)
  gemm_nt<128, 128, 64, 64, false, bf16><<<dim3(8, 8, 64), 256, 0, stream>>>(
      QKV, QKV + 1024, Sbuf, nullptr, 64, 3072, 3072, 1024,
      3145728, 64, 3145728, 64, 16L * 1048576, 1048576, 16, QK_SCALE);

  // 5) fused pre-mix + softmax + post-mix, in place on S
  mix_softmax_mix<<<dim3(1024, 4, 1), 256, 0, stream>>>(Sbuf, mpre, mpost);

  // 6) O_bG = P_bG @ V_bG  (z = b*16+G), written as [b*n+i][G*64+d]
  gemm_nt<128, 64, 64, 32, false, bf16><<<dim3(1, 8, 64), 256, 0, stream>>>(
      Sbuf, VT, Obuf, nullptr, 1024, 1024, 1024, 1024,
      16L * 1048576, 1048576, 16L * 65536, 65536, 1048576, 64, 16, 1.f);

  // 7) out = O @ Wo + bo  (fp32 output + fp32 bias, direct epilogue)
  gemm_nt<128, 128, 64, 64, true, float><<<dim3(8, 32, 1), 256, 0, stream>>>(
      Obuf, WoT, out, bo, 1024, 1024, 1024, 1024, 0, 0, 0, 0, 0, 0, 1, 1.f);
}